// Round 3
// baseline (611.907 us; speedup 1.0000x reference)
//
#include <hip/hip_runtime.h>
#include <stdint.h>

// CenterNet postprocess: y_pred (32, 84, 128, 128) f32 -> (32, 100, 8) f32
//
// Fast path (always runs):
//   k_pass1 : streaming screen v >= 3.0 over the 80 heatmap channels; for the
//             rare hits (~1750/batch) do the 3x3 NMS test via cache re-reads
//             and append (value,index) keys. NO histogram, NO LDS atomics
//             (round-2 post-mortem: hot-bin LDS histogram atomics serialized
//             the DS pipe -> 325us at 6% VALUBusy).
//   k_check : per batch, fast path valid iff MAXDET <= cnt <= CAP.
//   k_final : bitonic-sort candidates, top-100, gather coords, emit boxes.
// Fallback (early-exit no-ops unless k_check flags a batch):
//   k_fb_hist / k_fb_scan / k_fb_collect — exact histogram-threshold
//   re-collect (round-1 proven code), for arbitrary inputs.

#define NCLS   80
#define NCH    84
#define WD     128
#define HD     128
#define HWD    16384
#define NPB    (NCLS * HWD)     // 1310720 heatmap elements per batch
#define NBINS  4096
#define CAP    4096
#define MAXDET 100
#define NBATCH 32
#define STHR   3.0f             // static screen threshold (true p100 ~ 3.79)

// ws layout (bytes):
#define HIST_OFF 0              // 32*4096*4 = 524288
#define CNT_OFF  524288         // 128
#define NEED_OFF 524416         // 128
#define THR_OFF  524544         // 128
#define CAND_OFF 524672         // 32*4096*8 = 1048576
#define ZERO_BYTES 524544       // hist + cnt + need

__device__ __forceinline__ uint32_t fsort(float f) {
  uint32_t u = __float_as_uint(f);
  return u ^ ((u & 0x80000000u) ? 0xFFFFFFFFu : 0x80000000u);
}
__device__ __forceinline__ float funsort(uint32_t u) {
  uint32_t b = (u & 0x80000000u) ? (u ^ 0x80000000u) : ~u;
  return __uint_as_float(b);
}

// exact 3x3 NMS test + candidate append for heatmap element r of batch b
__device__ __forceinline__ void nms_try(const float* __restrict__ hmb, int b,
                                        int r, float v,
                                        uint64_t* __restrict__ cb,
                                        uint32_t* __restrict__ cnt) {
  int sp = r & (HWD - 1);
  int h = sp >> 7, w = sp & (WD - 1);
  const float* p = hmb + r;
  float m = v;
  bool wl = (w > 0), wr = (w < WD - 1);
  if (wl) m = fmaxf(m, p[-1]);
  if (wr) m = fmaxf(m, p[1]);
  if (h > 0) {
    m = fmaxf(m, p[-WD]);
    if (wl) m = fmaxf(m, p[-WD - 1]);
    if (wr) m = fmaxf(m, p[-WD + 1]);
  }
  if (h < HD - 1) {
    m = fmaxf(m, p[WD]);
    if (wl) m = fmaxf(m, p[WD - 1]);
    if (wr) m = fmaxf(m, p[WD + 1]);
  }
  if (v == m) {
    uint32_t u = fsort(v);
    uint32_t fi = (uint32_t)(sp * NCLS + (r >> 14));  // (H,W,C) flat index
    uint32_t pos = atomicAdd(&cnt[b], 1u);
    if (pos < CAP) cb[pos] = ((uint64_t)u << 32) | (uint32_t)(~fi);
  }
}

// ---------------- pass 1: streaming screen + rare NMS test ------------------
// grid (160, 32) x 256 threads; each block screens 8192 contiguous floats.
extern "C" __global__ __launch_bounds__(256)
void k_pass1(const float* __restrict__ in, uint64_t* __restrict__ cand,
             uint32_t* __restrict__ cnt) {
  const int b = blockIdx.y;
  const float* hmb = in + (size_t)b * NCH * HWD;
  uint64_t* cb = cand + (size_t)b * CAP;
  const int base = blockIdx.x * 8192 + (int)threadIdx.x * 4;

#pragma unroll
  for (int it = 0; it < 8; ++it) {
    int r = base + it * 1024;
    float4 v = *reinterpret_cast<const float4*>(hmb + r);
    if (v.x >= STHR) nms_try(hmb, b, r + 0, v.x, cb, cnt);
    if (v.y >= STHR) nms_try(hmb, b, r + 1, v.y, cb, cnt);
    if (v.z >= STHR) nms_try(hmb, b, r + 2, v.z, cb, cnt);
    if (v.w >= STHR) nms_try(hmb, b, r + 3, v.w, cb, cnt);
  }
}

// ---------------- check: is the fast path sufficient? -----------------------
extern "C" __global__ void k_check(uint32_t* __restrict__ cnt,
                                   uint32_t* __restrict__ need) {
  int b = threadIdx.x;
  if (b < NBATCH) {
    uint32_t c = cnt[b];
    uint32_t nd = (c < MAXDET) || (c > CAP);
    need[b] = nd;
    if (nd) cnt[b] = 0;  // fallback re-collects exactly
  }
}

// ---------------- fallback: exact histogram (round-1 proven) ----------------
extern "C" __global__ __launch_bounds__(256)
void k_fb_hist(const float* __restrict__ in, const uint32_t* __restrict__ need,
               uint32_t* __restrict__ hist) {
  int b = blockIdx.y;
  if (!need[b]) return;
  __shared__ uint32_t lh[NBINS];
  for (int i = threadIdx.x; i < NBINS; i += 256) lh[i] = 0;
  __syncthreads();

  const float* hmb = in + (size_t)b * NCH * HWD;
  int base = blockIdx.x * 4096;
  uint32_t zp = 0, zn = 0;
  for (int it = 0; it < 16; ++it) {
    int e = base + it * 256 + (int)threadIdx.x;
    int sp = e & (HWD - 1);
    int h = sp >> 7, w = sp & (WD - 1);
    const float* p = hmb + e;
    float v = p[0];
    float m = v;
    bool wl = (w > 0), wr = (w < WD - 1);
    if (wl) m = fmaxf(m, p[-1]);
    if (wr) m = fmaxf(m, p[1]);
    if (h > 0) {
      m = fmaxf(m, p[-WD]);
      if (wl) m = fmaxf(m, p[-WD - 1]);
      if (wr) m = fmaxf(m, p[-WD + 1]);
    }
    if (h < HD - 1) {
      m = fmaxf(m, p[WD]);
      if (wl) m = fmaxf(m, p[WD - 1]);
      if (wr) m = fmaxf(m, p[WD + 1]);
    }
    if (v == m) {
      atomicAdd(&lh[fsort(v) >> 20], 1u);
    } else if (__float_as_uint(v) >> 31) zn++; else zp++;
  }
  for (int off = 32; off; off >>= 1) {
    zp += __shfl_down(zp, off);
    zn += __shfl_down(zn, off);
  }
  if ((threadIdx.x & 63) == 0) {
    if (zp) atomicAdd(&lh[2048], zp);
    if (zn) atomicAdd(&lh[2047], zn);
  }
  __syncthreads();
  uint32_t* hb = hist + (size_t)b * NBINS;
  for (int i = threadIdx.x; i < NBINS; i += 256) {
    uint32_t v = lh[i];
    if (v) atomicAdd(&hb[i], v);
  }
}

extern "C" __global__ __launch_bounds__(256)
void k_fb_scan(const uint32_t* __restrict__ hist,
               const uint32_t* __restrict__ need, uint32_t* __restrict__ thr) {
  int b = blockIdx.x;
  if (!need[b]) return;
  int t = threadIdx.x;
  const uint32_t* hb = hist + (size_t)b * NBINS;
  __shared__ uint32_t ssum[256];
  __shared__ uint32_t sthr;
  if (t == 0) sthr = 0;
  const int PER = NBINS / 256;
  uint32_t loc[PER];
  uint32_t own = 0;
#pragma unroll
  for (int i = 0; i < PER; ++i) { loc[i] = hb[t * PER + i]; own += loc[i]; }
  ssum[t] = own;
  __syncthreads();
  if (t == 0) {
    uint32_t acc = 0;
    for (int j = 255; j >= 0; --j) { uint32_t v = ssum[j]; ssum[j] = acc; acc += v; }
  }
  __syncthreads();
  uint32_t above = ssum[t];
  if (above < MAXDET && above + own >= MAXDET) {
    uint32_t cum = above;
    for (int i = PER - 1; i >= 0; --i) {
      cum += loc[i];
      if (cum >= MAXDET) { sthr = (uint32_t)(t * PER + i); break; }
    }
  }
  __syncthreads();
  if (t == 0) thr[b] = sthr;
}

extern "C" __global__ __launch_bounds__(256)
void k_fb_collect(const float* __restrict__ in, const uint32_t* __restrict__ thr,
                  const uint32_t* __restrict__ need, uint64_t* __restrict__ cand,
                  uint32_t* __restrict__ cnt) {
  int b = blockIdx.y;
  if (!need[b]) return;
  uint32_t uthr = thr[b] << 20;
  const float* hmb = in + (size_t)b * NCH * HWD;
  int base = blockIdx.x * 32768;
  for (int it = 0; it < 128; ++it) {
    int e = base + it * 256 + (int)threadIdx.x;
    int sp = e & (HWD - 1);
    int h = sp >> 7, w = sp & (WD - 1);
    const float* p = hmb + e;
    float v = p[0];
    float m = v;
    bool wl = (w > 0), wr = (w < WD - 1);
    if (wl) m = fmaxf(m, p[-1]);
    if (wr) m = fmaxf(m, p[1]);
    if (h > 0) {
      m = fmaxf(m, p[-WD]);
      if (wl) m = fmaxf(m, p[-WD - 1]);
      if (wr) m = fmaxf(m, p[-WD + 1]);
    }
    if (h < HD - 1) {
      m = fmaxf(m, p[WD]);
      if (wl) m = fmaxf(m, p[WD - 1]);
      if (wr) m = fmaxf(m, p[WD + 1]);
    }
    bool kept = (v == m);
    float nv = kept ? v : 0.0f * v;
    uint32_t u = fsort(nv);
    if (u >= uthr) {
      uint32_t fi = (uint32_t)(sp * NCLS + (e >> 14));
      uint32_t pos = atomicAdd(&cnt[b], 1u);
      if (pos < CAP)
        cand[(size_t)b * CAP + pos] = ((uint64_t)u << 32) | (uint32_t)(~fi);
    }
  }
}

// ---------------- final: sort, select, gather, emit -------------------------
extern "C" __global__ __launch_bounds__(1024)
void k_final(const float* __restrict__ in, const uint64_t* __restrict__ cand,
             const uint32_t* __restrict__ cnt, float* __restrict__ out) {
  int b = blockIdx.x;
  __shared__ uint64_t sk[CAP];
  uint32_t n = cnt[b];
  if (n > CAP) n = CAP;
  uint32_t m = 128;
  while (m < n) m <<= 1;
  const uint64_t* cb = cand + (size_t)b * CAP;
  for (uint32_t i = threadIdx.x; i < m; i += 1024)
    sk[i] = (i < n) ? cb[i] : 0ull;  // key 0 sorts below all real keys
  __syncthreads();

  for (uint32_t k = 2; k <= m; k <<= 1) {
    for (uint32_t j = k >> 1; j > 0; j >>= 1) {
      for (uint32_t i = threadIdx.x; i < m; i += 1024) {
        uint32_t ixj = i ^ j;
        if (ixj > i && ixj < m) {
          uint64_t a = sk[i], c = sk[ixj];
          bool desc = (i & k) == 0;
          if (desc ? (a < c) : (a > c)) { sk[i] = c; sk[ixj] = a; }
        }
      }
      __syncthreads();
    }
  }

  if (threadIdx.x < MAXDET) {
    int j = threadIdx.x;
    uint64_t key = sk[j];
    uint32_t u = (uint32_t)(key >> 32);
    uint32_t fi = ~((uint32_t)key);
    float score = funsort(u);
    uint32_t c = fi % NCLS;
    uint32_t sp = (fi / NCLS) & (HWD - 1);
    float xs = (float)(sp & (WD - 1));
    float ys = (float)(sp >> 7);
    const float* gp = in + ((size_t)b * NCH + NCLS) * HWD + sp;
    float g0 = gp[0], g1 = gp[HWD], g2 = gp[2 * HWD], g3 = gp[3 * HWD];
    float* o = out + ((size_t)b * MAXDET + j) * 8;
    o[0] = (float)(c + 1);
    o[1] = score;
    o[2] = (4.0f * xs - g0) * (1.0f / 512.0f);
    o[3] = (4.0f * ys - g1) * (1.0f / 512.0f);
    o[4] = (4.0f * xs + g2) * (1.0f / 512.0f);
    o[5] = (4.0f * ys + g3) * (1.0f / 512.0f);
    o[6] = ys;
    o[7] = xs;
  }
}

extern "C" void kernel_launch(void* const* d_in, const int* in_sizes, int n_in,
                              void* d_out, int out_size, void* d_ws, size_t ws_size,
                              hipStream_t stream) {
  (void)in_sizes; (void)n_in; (void)out_size; (void)ws_size;
  const float* in = (const float*)d_in[0];
  float* out = (float*)d_out;
  uint8_t* ws = (uint8_t*)d_ws;

  uint32_t* hist = (uint32_t*)(ws + HIST_OFF);
  uint32_t* cnt  = (uint32_t*)(ws + CNT_OFF);
  uint32_t* need = (uint32_t*)(ws + NEED_OFF);
  uint32_t* thr  = (uint32_t*)(ws + THR_OFF);
  uint64_t* cand = (uint64_t*)(ws + CAND_OFF);

  hipMemsetAsync(ws, 0, ZERO_BYTES, stream);

  k_pass1<<<dim3(160, NBATCH), 256, 0, stream>>>(in, cand, cnt);
  k_check<<<1, 64, 0, stream>>>(cnt, need);
  k_fb_hist<<<dim3(320, NBATCH), 256, 0, stream>>>(in, need, hist);
  k_fb_scan<<<NBATCH, 256, 0, stream>>>(hist, need, thr);
  k_fb_collect<<<dim3(40, NBATCH), 256, 0, stream>>>(in, thr, need, cand, cnt);
  k_final<<<NBATCH, 1024, 0, stream>>>(in, cand, cnt, out);
}

// Round 4
// 89.699 us; speedup vs baseline: 6.8218x; 6.8218x over previous
//
#include <hip/hip_runtime.h>
#include <stdint.h>

// CenterNet postprocess: y_pred (32, 84, 128, 128) f32 -> (32, 100, 8) f32
//
// Round-4 theory: round-3's 565us @ 0.9% VALUBusy was ~51K device-scope
// atomicAdds into one shared cache line (cnt[0..31]) serialized at the
// coherence point. Fix: per-block LDS candidate buffer, ONE global atomic
// per block, per-batch counters padded to 256B lines.
//
// Fast path (always runs):
//   k_pass1 : stream-screen v >= 3.0; hits (expected ~11/block) are NMS-tested
//             and buffered in LDS; one padded global atomic + coalesced flush.
//   k_check : fast path valid iff MAXDET <= cnt <= CAP (overflow poisons cnt).
//   k_final : bitonic-sort candidates, top-100, gather coords, emit boxes.
// Fallback (early-exit no-ops unless k_check flags a batch): exact
//   histogram-threshold re-collect (round-1 proven code).

#define NCLS   80
#define NCH    84
#define WD     128
#define HD     128
#define HWD    16384
#define NPB    (NCLS * HWD)     // 1310720 heatmap elements per batch
#define NBINS  4096
#define CAP    4096
#define MAXDET 100
#define NBATCH 32
#define STHR   3.0f             // static screen threshold (true p100 ~ 3.79)
#define BUFSZ  256              // per-block LDS candidate buffer
#define CNTS   64               // cnt stride in u32 (256B per batch)

// ws layout (bytes):
#define HIST_OFF 0              // 32*4096*4 = 524288
#define CNT_OFF  524288         // 32*64*4   = 8192
#define NEED_OFF 532480         // 128
#define THR_OFF  532608         // 128
#define CAND_OFF 532736         // 32*4096*8 = 1048576
#define ZERO_OFF CNT_OFF        // memset covers cnt + need only (8320 B)
#define ZERO_BYTES (8192 + 128)

__device__ __forceinline__ uint32_t fsort(float f) {
  uint32_t u = __float_as_uint(f);
  return u ^ ((u & 0x80000000u) ? 0xFFFFFFFFu : 0x80000000u);
}
__device__ __forceinline__ float funsort(uint32_t u) {
  uint32_t b = (u & 0x80000000u) ? (u ^ 0x80000000u) : ~u;
  return __uint_as_float(b);
}

// exact 3x3 NMS test; on success append key to the block's LDS buffer
__device__ __forceinline__ void nms_try(const float* __restrict__ hmb, int r,
                                        float v, uint64_t* __restrict__ lbuf,
                                        uint32_t* __restrict__ lcnt) {
  int sp = r & (HWD - 1);
  int h = sp >> 7, w = sp & (WD - 1);
  const float* p = hmb + r;
  float m = v;
  bool wl = (w > 0), wr = (w < WD - 1);
  if (wl) m = fmaxf(m, p[-1]);
  if (wr) m = fmaxf(m, p[1]);
  if (h > 0) {
    m = fmaxf(m, p[-WD]);
    if (wl) m = fmaxf(m, p[-WD - 1]);
    if (wr) m = fmaxf(m, p[-WD + 1]);
  }
  if (h < HD - 1) {
    m = fmaxf(m, p[WD]);
    if (wl) m = fmaxf(m, p[WD - 1]);
    if (wr) m = fmaxf(m, p[WD + 1]);
  }
  if (v == m) {
    uint32_t u = fsort(v);
    uint32_t fi = (uint32_t)(sp * NCLS + (r >> 14));  // (H,W,C) flat index
    uint32_t pos = atomicAdd(lcnt, 1u);
    if (pos < BUFSZ) lbuf[pos] = ((uint64_t)u << 32) | (uint32_t)(~fi);
  }
}

// ---------------- pass 1: streaming screen + LDS-buffered collect -----------
// grid (160, 32) x 256 threads; each block screens 8192 contiguous floats.
extern "C" __global__ __launch_bounds__(256)
void k_pass1(const float* __restrict__ in, uint64_t* __restrict__ cand,
             uint32_t* __restrict__ cnt) {
  __shared__ uint32_t lcnt, lbase;
  __shared__ uint64_t lbuf[BUFSZ];
  if (threadIdx.x == 0) lcnt = 0;
  __syncthreads();

  const int b = blockIdx.y;
  const float* hmb = in + (size_t)b * NCH * HWD;
  const int base = blockIdx.x * 8192 + (int)threadIdx.x * 4;

  float4 v[8];
#pragma unroll
  for (int it = 0; it < 8; ++it)
    v[it] = *reinterpret_cast<const float4*>(hmb + base + it * 1024);

#pragma unroll
  for (int it = 0; it < 8; ++it) {
    int r = base + it * 1024;
    if (v[it].x >= STHR) nms_try(hmb, r + 0, v[it].x, lbuf, &lcnt);
    if (v[it].y >= STHR) nms_try(hmb, r + 1, v[it].y, lbuf, &lcnt);
    if (v[it].z >= STHR) nms_try(hmb, r + 2, v[it].z, lbuf, &lcnt);
    if (v[it].w >= STHR) nms_try(hmb, r + 3, v[it].w, lbuf, &lcnt);
  }
  __syncthreads();

  if (threadIdx.x == 0) {
    uint32_t n = lcnt;
    // poison: overflowed blocks force cnt > CAP so k_check triggers fallback
    uint32_t add = (n <= BUFSZ) ? n : (BUFSZ + CAP + 1);
    lbase = atomicAdd(&cnt[(size_t)b * CNTS], add);
  }
  __syncthreads();

  uint32_t n = lcnt;
  if (n > BUFSZ) n = BUFSZ;
  uint32_t bs = lbase;
  uint64_t* cb = cand + (size_t)b * CAP;
  for (uint32_t i = threadIdx.x; i < n; i += 256) {
    uint32_t pos = bs + i;
    if (pos < CAP) cb[pos] = lbuf[i];
  }
}

// ---------------- check: is the fast path sufficient? -----------------------
extern "C" __global__ void k_check(uint32_t* __restrict__ cnt,
                                   uint32_t* __restrict__ need) {
  int b = threadIdx.x;
  if (b < NBATCH) {
    uint32_t c = cnt[(size_t)b * CNTS];
    uint32_t nd = (c < MAXDET) || (c > CAP);
    need[b] = nd;
    if (nd) cnt[(size_t)b * CNTS] = 0;  // fallback re-collects exactly
  }
}

// ---------------- fallback chain (early-exit no-ops normally) ---------------
extern "C" __global__ __launch_bounds__(256)
void k_fb_zero(const uint32_t* __restrict__ need, uint32_t* __restrict__ hist) {
  int b = blockIdx.x;
  if (!need[b]) return;
  uint32_t* hb = hist + (size_t)b * NBINS;
  for (int i = threadIdx.x; i < NBINS; i += 256) hb[i] = 0;
}

extern "C" __global__ __launch_bounds__(256)
void k_fb_hist(const float* __restrict__ in, const uint32_t* __restrict__ need,
               uint32_t* __restrict__ hist) {
  int b = blockIdx.y;
  if (!need[b]) return;
  __shared__ uint32_t lh[NBINS];
  for (int i = threadIdx.x; i < NBINS; i += 256) lh[i] = 0;
  __syncthreads();

  const float* hmb = in + (size_t)b * NCH * HWD;
  int base = blockIdx.x * 4096;
  uint32_t zp = 0, zn = 0;
  for (int it = 0; it < 16; ++it) {
    int e = base + it * 256 + (int)threadIdx.x;
    int sp = e & (HWD - 1);
    int h = sp >> 7, w = sp & (WD - 1);
    const float* p = hmb + e;
    float v = p[0];
    float m = v;
    bool wl = (w > 0), wr = (w < WD - 1);
    if (wl) m = fmaxf(m, p[-1]);
    if (wr) m = fmaxf(m, p[1]);
    if (h > 0) {
      m = fmaxf(m, p[-WD]);
      if (wl) m = fmaxf(m, p[-WD - 1]);
      if (wr) m = fmaxf(m, p[-WD + 1]);
    }
    if (h < HD - 1) {
      m = fmaxf(m, p[WD]);
      if (wl) m = fmaxf(m, p[WD - 1]);
      if (wr) m = fmaxf(m, p[WD + 1]);
    }
    if (v == m) {
      atomicAdd(&lh[fsort(v) >> 20], 1u);
    } else if (__float_as_uint(v) >> 31) zn++; else zp++;
  }
  for (int off = 32; off; off >>= 1) {
    zp += __shfl_down(zp, off);
    zn += __shfl_down(zn, off);
  }
  if ((threadIdx.x & 63) == 0) {
    if (zp) atomicAdd(&lh[2048], zp);
    if (zn) atomicAdd(&lh[2047], zn);
  }
  __syncthreads();
  uint32_t* hb = hist + (size_t)b * NBINS;
  for (int i = threadIdx.x; i < NBINS; i += 256) {
    uint32_t v = lh[i];
    if (v) atomicAdd(&hb[i], v);
  }
}

extern "C" __global__ __launch_bounds__(256)
void k_fb_scan(const uint32_t* __restrict__ hist,
               const uint32_t* __restrict__ need, uint32_t* __restrict__ thr) {
  int b = blockIdx.x;
  if (!need[b]) return;
  int t = threadIdx.x;
  const uint32_t* hb = hist + (size_t)b * NBINS;
  __shared__ uint32_t ssum[256];
  __shared__ uint32_t sthr;
  if (t == 0) sthr = 0;
  const int PER = NBINS / 256;
  uint32_t loc[PER];
  uint32_t own = 0;
#pragma unroll
  for (int i = 0; i < PER; ++i) { loc[i] = hb[t * PER + i]; own += loc[i]; }
  ssum[t] = own;
  __syncthreads();
  if (t == 0) {
    uint32_t acc = 0;
    for (int j = 255; j >= 0; --j) { uint32_t v = ssum[j]; ssum[j] = acc; acc += v; }
  }
  __syncthreads();
  uint32_t above = ssum[t];
  if (above < MAXDET && above + own >= MAXDET) {
    uint32_t cum = above;
    for (int i = PER - 1; i >= 0; --i) {
      cum += loc[i];
      if (cum >= MAXDET) { sthr = (uint32_t)(t * PER + i); break; }
    }
  }
  __syncthreads();
  if (t == 0) thr[b] = sthr;
}

extern "C" __global__ __launch_bounds__(256)
void k_fb_collect(const float* __restrict__ in, const uint32_t* __restrict__ thr,
                  const uint32_t* __restrict__ need, uint64_t* __restrict__ cand,
                  uint32_t* __restrict__ cnt) {
  int b = blockIdx.y;
  if (!need[b]) return;
  uint32_t uthr = thr[b] << 20;
  const float* hmb = in + (size_t)b * NCH * HWD;
  int base = blockIdx.x * 32768;
  for (int it = 0; it < 128; ++it) {
    int e = base + it * 256 + (int)threadIdx.x;
    int sp = e & (HWD - 1);
    int h = sp >> 7, w = sp & (WD - 1);
    const float* p = hmb + e;
    float v = p[0];
    float m = v;
    bool wl = (w > 0), wr = (w < WD - 1);
    if (wl) m = fmaxf(m, p[-1]);
    if (wr) m = fmaxf(m, p[1]);
    if (h > 0) {
      m = fmaxf(m, p[-WD]);
      if (wl) m = fmaxf(m, p[-WD - 1]);
      if (wr) m = fmaxf(m, p[-WD + 1]);
    }
    if (h < HD - 1) {
      m = fmaxf(m, p[WD]);
      if (wl) m = fmaxf(m, p[WD - 1]);
      if (wr) m = fmaxf(m, p[WD + 1]);
    }
    bool kept = (v == m);
    float nv = kept ? v : 0.0f * v;
    uint32_t u = fsort(nv);
    if (u >= uthr) {
      uint32_t fi = (uint32_t)(sp * NCLS + (e >> 14));
      uint32_t pos = atomicAdd(&cnt[(size_t)b * CNTS], 1u);
      if (pos < CAP)
        cand[(size_t)b * CAP + pos] = ((uint64_t)u << 32) | (uint32_t)(~fi);
    }
  }
}

// ---------------- final: sort, select, gather, emit -------------------------
extern "C" __global__ __launch_bounds__(1024)
void k_final(const float* __restrict__ in, const uint64_t* __restrict__ cand,
             const uint32_t* __restrict__ cnt, float* __restrict__ out) {
  int b = blockIdx.x;
  __shared__ uint64_t sk[CAP];
  uint32_t n = cnt[(size_t)b * CNTS];
  if (n > CAP) n = CAP;
  uint32_t m = 128;
  while (m < n) m <<= 1;
  const uint64_t* cb = cand + (size_t)b * CAP;
  for (uint32_t i = threadIdx.x; i < m; i += 1024)
    sk[i] = (i < n) ? cb[i] : 0ull;  // key 0 sorts below all real keys
  __syncthreads();

  for (uint32_t k = 2; k <= m; k <<= 1) {
    for (uint32_t j = k >> 1; j > 0; j >>= 1) {
      for (uint32_t i = threadIdx.x; i < m; i += 1024) {
        uint32_t ixj = i ^ j;
        if (ixj > i && ixj < m) {
          uint64_t a = sk[i], c = sk[ixj];
          bool desc = (i & k) == 0;
          if (desc ? (a < c) : (a > c)) { sk[i] = c; sk[ixj] = a; }
        }
      }
      __syncthreads();
    }
  }

  if (threadIdx.x < MAXDET) {
    int j = threadIdx.x;
    uint64_t key = sk[j];
    uint32_t u = (uint32_t)(key >> 32);
    uint32_t fi = ~((uint32_t)key);
    float score = funsort(u);
    uint32_t c = fi % NCLS;
    uint32_t sp = (fi / NCLS) & (HWD - 1);
    float xs = (float)(sp & (WD - 1));
    float ys = (float)(sp >> 7);
    const float* gp = in + ((size_t)b * NCH + NCLS) * HWD + sp;
    float g0 = gp[0], g1 = gp[HWD], g2 = gp[2 * HWD], g3 = gp[3 * HWD];
    float* o = out + ((size_t)b * MAXDET + j) * 8;
    o[0] = (float)(c + 1);
    o[1] = score;
    o[2] = (4.0f * xs - g0) * (1.0f / 512.0f);
    o[3] = (4.0f * ys - g1) * (1.0f / 512.0f);
    o[4] = (4.0f * xs + g2) * (1.0f / 512.0f);
    o[5] = (4.0f * ys + g3) * (1.0f / 512.0f);
    o[6] = ys;
    o[7] = xs;
  }
}

extern "C" void kernel_launch(void* const* d_in, const int* in_sizes, int n_in,
                              void* d_out, int out_size, void* d_ws, size_t ws_size,
                              hipStream_t stream) {
  (void)in_sizes; (void)n_in; (void)out_size; (void)ws_size;
  const float* in = (const float*)d_in[0];
  float* out = (float*)d_out;
  uint8_t* ws = (uint8_t*)d_ws;

  uint32_t* hist = (uint32_t*)(ws + HIST_OFF);
  uint32_t* cnt  = (uint32_t*)(ws + CNT_OFF);
  uint32_t* need = (uint32_t*)(ws + NEED_OFF);
  uint32_t* thr  = (uint32_t*)(ws + THR_OFF);
  uint64_t* cand = (uint64_t*)(ws + CAND_OFF);

  hipMemsetAsync(ws + ZERO_OFF, 0, ZERO_BYTES, stream);

  k_pass1<<<dim3(160, NBATCH), 256, 0, stream>>>(in, cand, cnt);
  k_check<<<1, 64, 0, stream>>>(cnt, need);
  k_fb_zero<<<NBATCH, 256, 0, stream>>>(need, hist);
  k_fb_hist<<<dim3(320, NBATCH), 256, 0, stream>>>(in, need, hist);
  k_fb_scan<<<NBATCH, 256, 0, stream>>>(hist, need, thr);
  k_fb_collect<<<dim3(40, NBATCH), 256, 0, stream>>>(in, thr, need, cand, cnt);
  k_final<<<NBATCH, 1024, 0, stream>>>(in, cand, cnt, out);
}

// Round 5
// 51.569 us; speedup vs baseline: 11.8658x; 1.7394x over previous
//
#include <hip/hip_runtime.h>
#include <stdint.h>

// CenterNet postprocess: y_pred (32, 84, 128, 128) f32 -> (32, 100, 8) f32
//
// Round-5: consolidate dispatch overhead. 3 dispatches total:
//   memset(8KB) -> k_pass1 (screen+collect) -> k_finalize (check+sort+emit,
//   with a fully in-block exact fallback for arbitrary inputs).
//
// k_pass1: stream-screen v >= 3.4 (true p100 ~ 3.79); rare hits (~440/batch)
//   are 3x3-NMS-tested via cache re-reads, buffered in LDS, flushed with ONE
//   padded global atomic per block (round-4 lesson: same-line device atomics
//   serialize ~10ns each at the coherence point).
// k_finalize: per batch, if cnt in [100, CAP] sort candidates and emit top-100
//   (exact lax.top_k order via (value,~index) keys); else run the exact
//   in-block histogram-threshold re-collect first (never taken on bench data).

#define NCLS   80
#define NCH    84
#define WD     128
#define HD     128
#define HWD    16384
#define NPB    (NCLS * HWD)     // 1310720 heatmap elements per batch
#define NBINS  4096
#define CAP    4096
#define MAXDET 100
#define NBATCH 32
#define STHR   3.4f
#define BUFSZ  256              // per-block LDS candidate buffer in pass1
#define CNTS   64               // cnt stride in u32 (256B per batch)

// ws layout (bytes):
#define CNT_OFF  0              // 32*64*4 = 8192
#define CAND_OFF 8192           // 32*4096*8 = 1048576
#define ZERO_BYTES 8192

__device__ __forceinline__ uint32_t fsort(float f) {
  uint32_t u = __float_as_uint(f);
  return u ^ ((u & 0x80000000u) ? 0xFFFFFFFFu : 0x80000000u);
}
__device__ __forceinline__ float funsort(uint32_t u) {
  uint32_t b = (u & 0x80000000u) ? (u ^ 0x80000000u) : ~u;
  return __uint_as_float(b);
}

// exact 3x3 NMS max-of-neighbors for heatmap element e (within one batch)
__device__ __forceinline__ float nms_nbmax(const float* __restrict__ hmb, int e,
                                           float v) {
  int sp = e & (HWD - 1);
  int h = sp >> 7, w = sp & (WD - 1);
  const float* p = hmb + e;
  float m = v;
  bool wl = (w > 0), wr = (w < WD - 1);
  if (wl) m = fmaxf(m, p[-1]);
  if (wr) m = fmaxf(m, p[1]);
  if (h > 0) {
    m = fmaxf(m, p[-WD]);
    if (wl) m = fmaxf(m, p[-WD - 1]);
    if (wr) m = fmaxf(m, p[-WD + 1]);
  }
  if (h < HD - 1) {
    m = fmaxf(m, p[WD]);
    if (wl) m = fmaxf(m, p[WD - 1]);
    if (wr) m = fmaxf(m, p[WD + 1]);
  }
  return m;
}

__device__ __forceinline__ uint64_t make_key(uint32_t u, int e) {
  int sp = e & (HWD - 1);
  uint32_t fi = (uint32_t)(sp * NCLS + (e >> 14));  // (H,W,C) flat index
  return ((uint64_t)u << 32) | (uint32_t)(~fi);
}

// ---------------- pass 1: streaming screen + LDS-buffered collect -----------
// grid (160, 32) x 256 threads; each block screens 8192 contiguous floats.
extern "C" __global__ __launch_bounds__(256)
void k_pass1(const float* __restrict__ in, uint64_t* __restrict__ cand,
             uint32_t* __restrict__ cnt) {
  __shared__ uint32_t lcnt, lbase;
  __shared__ uint64_t lbuf[BUFSZ];
  if (threadIdx.x == 0) lcnt = 0;
  __syncthreads();

  const int b = blockIdx.y;
  const float* hmb = in + (size_t)b * NCH * HWD;
  const int base = blockIdx.x * 8192 + (int)threadIdx.x * 4;

  float4 v[8];
#pragma unroll
  for (int it = 0; it < 8; ++it)
    v[it] = *reinterpret_cast<const float4*>(hmb + base + it * 1024);

#pragma unroll
  for (int it = 0; it < 8; ++it) {
    int r = base + it * 1024;
#define TRY(vi, off)                                                     \
    if (vi >= STHR && vi == nms_nbmax(hmb, r + off, vi)) {               \
      uint32_t pos = atomicAdd(&lcnt, 1u);                               \
      if (pos < BUFSZ) lbuf[pos] = make_key(fsort(vi), r + off);         \
    }
    TRY(v[it].x, 0) TRY(v[it].y, 1) TRY(v[it].z, 2) TRY(v[it].w, 3)
#undef TRY
  }
  __syncthreads();

  if (threadIdx.x == 0) {
    uint32_t n = lcnt;
    // overflowed block (n > BUFSZ) poisons cnt so k_finalize takes fallback
    uint32_t add = (n <= BUFSZ) ? n : (BUFSZ + CAP + 1);
    lbase = atomicAdd(&cnt[(size_t)b * CNTS], add);
  }
  __syncthreads();

  uint32_t n = lcnt;
  if (n > BUFSZ) n = BUFSZ;
  uint32_t bs = lbase;
  uint64_t* cb = cand + (size_t)b * CAP;
  for (uint32_t i = threadIdx.x; i < n; i += 256) {
    uint32_t pos = bs + i;
    if (pos < CAP) cb[pos] = lbuf[i];
  }
}

// ---------------- finalize: check (+exact fallback) + sort + emit -----------
extern "C" __global__ __launch_bounds__(1024)
void k_finalize(const float* __restrict__ in, const uint64_t* __restrict__ cand,
                uint32_t* __restrict__ cnt, float* __restrict__ out) {
  const int b = blockIdx.x;
  const int t = threadIdx.x;
  const float* hmb = in + (size_t)b * NCH * HWD;

  __shared__ uint64_t sk[CAP];      // 32 KB
  __shared__ uint32_t hist[NBINS];  // 16 KB (fallback only)
  __shared__ uint32_t scn[1024];    // 4 KB  (fallback only)
  __shared__ uint32_t sthr_s, lcnt;

  uint32_t n = cnt[(size_t)b * CNTS];
  bool fb = (n < MAXDET) || (n > CAP);

  if (!fb) {
    const uint64_t* cb = cand + (size_t)b * CAP;
    uint32_t m = 128; while (m < n) m <<= 1;
    for (uint32_t i = t; i < m; i += 1024) sk[i] = (i < n) ? cb[i] : 0ull;
  } else {
    // ---- exact in-block fallback (arbitrary inputs; never taken on bench) --
    for (int i = t; i < NBINS; i += 1024) hist[i] = 0;
    __syncthreads();
    uint32_t zp = 0, zn = 0;
    for (int e = t; e < NPB; e += 1024) {
      float v = hmb[e];
      if (v == nms_nbmax(hmb, e, v)) {
        atomicAdd(&hist[fsort(v) >> 20], 1u);
      } else if (__float_as_uint(v) >> 31) zn++; else zp++;
    }
    for (int off = 32; off; off >>= 1) {
      zp += __shfl_down(zp, off);
      zn += __shfl_down(zn, off);
    }
    if ((t & 63) == 0) {
      if (zp) atomicAdd(&hist[2048], zp);  // suppressed +0.0
      if (zn) atomicAdd(&hist[2047], zn);  // suppressed -0.0
    }
    __syncthreads();
    // suffix scan over 4096 bins, 4 bins/thread
    uint32_t loc[4], own = 0;
#pragma unroll
    for (int i = 0; i < 4; ++i) { loc[i] = hist[t * 4 + i]; own += loc[i]; }
    scn[t] = own;
    if (t == 0) { sthr_s = 0; lcnt = 0; }
    __syncthreads();
    if (t == 0) {
      uint32_t acc = 0;
      for (int j = 1023; j >= 0; --j) { uint32_t v = scn[j]; scn[j] = acc; acc += v; }
    }
    __syncthreads();
    uint32_t above = scn[t];
    if (above < MAXDET && above + own >= MAXDET) {
      uint32_t cum = above;
      for (int i = 3; i >= 0; --i) {
        cum += loc[i];
        if (cum >= MAXDET) { sthr_s = (uint32_t)(t * 4 + i); break; }
      }
    }
    __syncthreads();
    uint32_t uthr = sthr_s << 20;
    for (int e = t; e < NPB; e += 1024) {
      float v = hmb[e];
      bool kept = (v == nms_nbmax(hmb, e, v));
      float nv = kept ? v : 0.0f * v;
      uint32_t u = fsort(nv);
      if (u >= uthr) {
        uint32_t pos = atomicAdd(&lcnt, 1u);
        if (pos < CAP) sk[pos] = make_key(u, e);
      }
    }
    __syncthreads();
    n = lcnt; if (n > CAP) n = CAP;
    uint32_t m = 128; while (m < n) m <<= 1;
    for (uint32_t i = t; i < m; i += 1024) if (i >= n) sk[i] = 0ull;
  }
  __syncthreads();

  uint32_t m = 128; while (m < n) m <<= 1;
  // bitonic sort descending by (value, ~fi): value desc, index asc on ties
  for (uint32_t k = 2; k <= m; k <<= 1) {
    for (uint32_t j = k >> 1; j > 0; j >>= 1) {
      for (uint32_t i = t; i < m; i += 1024) {
        uint32_t ixj = i ^ j;
        if (ixj > i && ixj < m) {
          uint64_t a = sk[i], c = sk[ixj];
          bool desc = (i & k) == 0;
          if (desc ? (a < c) : (a > c)) { sk[i] = c; sk[ixj] = a; }
        }
      }
      __syncthreads();
    }
  }

  if (t < MAXDET) {
    uint64_t key = sk[t];
    uint32_t u = (uint32_t)(key >> 32);
    uint32_t fi = ~((uint32_t)key);
    float score = funsort(u);
    uint32_t c = fi % NCLS;
    uint32_t sp = (fi / NCLS) & (HWD - 1);
    float xs = (float)(sp & (WD - 1));
    float ys = (float)(sp >> 7);
    const float* gp = in + ((size_t)b * NCH + NCLS) * HWD + sp;
    float g0 = gp[0], g1 = gp[HWD], g2 = gp[2 * HWD], g3 = gp[3 * HWD];
    float* o = out + ((size_t)b * MAXDET + t) * 8;
    o[0] = (float)(c + 1);
    o[1] = score;
    o[2] = (4.0f * xs - g0) * (1.0f / 512.0f);
    o[3] = (4.0f * ys - g1) * (1.0f / 512.0f);
    o[4] = (4.0f * xs + g2) * (1.0f / 512.0f);
    o[5] = (4.0f * ys + g3) * (1.0f / 512.0f);
    o[6] = ys;
    o[7] = xs;
  }
}

extern "C" void kernel_launch(void* const* d_in, const int* in_sizes, int n_in,
                              void* d_out, int out_size, void* d_ws, size_t ws_size,
                              hipStream_t stream) {
  (void)in_sizes; (void)n_in; (void)out_size; (void)ws_size;
  const float* in = (const float*)d_in[0];
  float* out = (float*)d_out;
  uint8_t* ws = (uint8_t*)d_ws;

  uint32_t* cnt  = (uint32_t*)(ws + CNT_OFF);
  uint64_t* cand = (uint64_t*)(ws + CAND_OFF);

  hipMemsetAsync(ws, 0, ZERO_BYTES, stream);
  k_pass1<<<dim3(160, NBATCH), 256, 0, stream>>>(in, cand, cnt);
  k_finalize<<<NBATCH, 1024, 0, stream>>>(in, cand, cnt, out);
}

// Round 6
// 43.054 us; speedup vs baseline: 14.2126x; 1.1978x over previous
//
#include <hip/hip_runtime.h>
#include <stdint.h>

// CenterNet postprocess: y_pred (32, 84, 128, 128) f32 -> (32, 100, 8) f32
//
// Round-6: 2 dispatches, no memset, no global atomics.
//   k_pass1 : stream-screen v >= 3.6 (per-float4 max-guard); rare hits
//             (~208/batch expected) are 3x3-NMS-tested and stored to a
//             PRIVATE 32-slot region of cand per block; per-block count
//             written unconditionally (no zero-init, no atomics).
//   k_finalize (256 thr, 1 block/batch): prefix-sum the 160 block counts,
//             gather candidates, bitonic-sort (value,~index) keys, emit
//             top-100 in exact lax.top_k order. If any block overflowed or
//             total count is out of [100, 4096]: exact in-block
//             histogram-threshold fallback (never taken on bench data).

#define NCLS   80
#define NCH    84
#define WD     128
#define HD     128
#define HWD    16384
#define NPB    (NCLS * HWD)     // 1310720 heatmap elements per batch
#define NBINS  4096
#define SKCAP  4096
#define MAXDET 100
#define NBATCH 32
#define STHR   3.6f             // static screen threshold (true p100 ~ 3.79)
#define NBLK   160              // pass1 blocks per batch
#define SLOT   32               // candidate slots per pass1 block

// ws layout (bytes):
#define CNT_OFF  0              // 32*160*4 = 20480  (pad to 32768)
#define CAND_OFF 32768          // 32*160*32*8 = 1310720
// total 1343488

__device__ __forceinline__ uint32_t fsort(float f) {
  uint32_t u = __float_as_uint(f);
  return u ^ ((u & 0x80000000u) ? 0xFFFFFFFFu : 0x80000000u);
}
__device__ __forceinline__ float funsort(uint32_t u) {
  uint32_t b = (u & 0x80000000u) ? (u ^ 0x80000000u) : ~u;
  return __uint_as_float(b);
}

// exact 3x3 NMS max-of-neighbors for heatmap element e (within one batch)
__device__ __forceinline__ float nms_nbmax(const float* __restrict__ hmb, int e,
                                           float v) {
  int sp = e & (HWD - 1);
  int h = sp >> 7, w = sp & (WD - 1);
  const float* p = hmb + e;
  float m = v;
  bool wl = (w > 0), wr = (w < WD - 1);
  if (wl) m = fmaxf(m, p[-1]);
  if (wr) m = fmaxf(m, p[1]);
  if (h > 0) {
    m = fmaxf(m, p[-WD]);
    if (wl) m = fmaxf(m, p[-WD - 1]);
    if (wr) m = fmaxf(m, p[-WD + 1]);
  }
  if (h < HD - 1) {
    m = fmaxf(m, p[WD]);
    if (wl) m = fmaxf(m, p[WD - 1]);
    if (wr) m = fmaxf(m, p[WD + 1]);
  }
  return m;
}

__device__ __forceinline__ uint64_t make_key(uint32_t u, int e) {
  int sp = e & (HWD - 1);
  uint32_t fi = (uint32_t)(sp * NCLS + (e >> 14));  // (H,W,C) flat index
  return ((uint64_t)u << 32) | (uint32_t)(~fi);
}

// ---------------- pass 1: streaming screen, private-slot collect ------------
// grid (160, 32) x 256 threads; each block screens 8192 contiguous floats.
extern "C" __global__ __launch_bounds__(256)
void k_pass1(const float* __restrict__ in, uint64_t* __restrict__ cand,
             uint32_t* __restrict__ cnt) {
  __shared__ uint32_t lcnt;
  __shared__ uint64_t lbuf[SLOT];
  if (threadIdx.x == 0) lcnt = 0;
  __syncthreads();

  const int b = blockIdx.y;
  const int blk = blockIdx.x;
  const float* hmb = in + (size_t)b * NCH * HWD;
  const int base = blk * 8192 + (int)threadIdx.x * 4;

  float4 v[8];
#pragma unroll
  for (int it = 0; it < 8; ++it)
    v[it] = *reinterpret_cast<const float4*>(hmb + base + it * 1024);

#pragma unroll
  for (int it = 0; it < 8; ++it) {
    float4 w = v[it];
    float m4 = fmaxf(fmaxf(w.x, w.y), fmaxf(w.z, w.w));
    if (m4 >= STHR) {  // rare: one branch guards the detailed checks
      int r = base + it * 1024;
#define TRY(vi, off)                                                     \
      if (vi >= STHR && vi == nms_nbmax(hmb, r + off, vi)) {             \
        uint32_t pos = atomicAdd(&lcnt, 1u);                             \
        if (pos < SLOT) lbuf[pos] = make_key(fsort(vi), r + off);        \
      }
      TRY(w.x, 0) TRY(w.y, 1) TRY(w.z, 2) TRY(w.w, 3)
#undef TRY
    }
  }
  __syncthreads();

  uint32_t n = lcnt;
  uint64_t* cb = cand + ((size_t)b * NBLK + blk) * SLOT;
  uint32_t nn = (n < SLOT) ? n : SLOT;
  for (uint32_t i = threadIdx.x; i < nn; i += 256) cb[i] = lbuf[i];
  // raw count (may exceed SLOT -> finalize takes exact fallback)
  if (threadIdx.x == 0) cnt[(size_t)b * NBLK + blk] = n;
}

// ---------------- finalize: gather (+exact fallback) + sort + emit ----------
extern "C" __global__ __launch_bounds__(256)
void k_finalize(const float* __restrict__ in, const uint64_t* __restrict__ cand,
                const uint32_t* __restrict__ cnt, float* __restrict__ out) {
  const int b = blockIdx.x;
  const int t = threadIdx.x;
  const float* hmb = in + (size_t)b * NCH * HWD;

  __shared__ uint64_t sk[SKCAP];       // 32 KB
  __shared__ uint32_t hist[NBINS];     // 16 KB (fallback only)
  __shared__ uint32_t pfx[NBLK + 1];   // block-count prefix sums
  __shared__ uint32_t scnB[256];       // fallback bin scan
  __shared__ uint32_t flags, sthr_s, lcnt;

  if (t == 0) { flags = 0; sthr_s = 0; lcnt = 0; }
  __syncthreads();

  if (t < NBLK) {
    uint32_t c = cnt[(size_t)b * NBLK + t];
    if (c > SLOT) atomicOr(&flags, 1u);
    pfx[t] = c;
  }
  __syncthreads();
  if (t == 0) {
    uint32_t acc = 0;
    for (int i = 0; i < NBLK; ++i) { uint32_t u = pfx[i]; pfx[i] = acc; acc += u; }
    pfx[NBLK] = acc;
  }
  __syncthreads();

  uint32_t n = pfx[NBLK];
  bool fb = (flags != 0) || (n < MAXDET) || (n > SKCAP);

  if (!fb) {
    // gather per-block segments into contiguous sk[0..n)
    const uint64_t* cb = cand + (size_t)b * NBLK * SLOT;
    for (int i = t; i < NBLK; i += 256) {
      uint32_t off = pfx[i], ci = pfx[i + 1] - off;
      for (uint32_t j = 0; j < ci; ++j) sk[off + j] = cb[(size_t)i * SLOT + j];
    }
  } else {
    // ---- exact in-block fallback (arbitrary inputs; never taken on bench) --
    for (int i = t; i < NBINS; i += 256) hist[i] = 0;
    __syncthreads();
    uint32_t zp = 0, zn = 0;
    for (int e = t; e < NPB; e += 256) {
      float v = hmb[e];
      if (v == nms_nbmax(hmb, e, v)) {
        atomicAdd(&hist[fsort(v) >> 20], 1u);
      } else if (__float_as_uint(v) >> 31) zn++; else zp++;
    }
    for (int off = 32; off; off >>= 1) {
      zp += __shfl_down(zp, off);
      zn += __shfl_down(zn, off);
    }
    if ((t & 63) == 0) {
      if (zp) atomicAdd(&hist[2048], zp);  // suppressed +0.0
      if (zn) atomicAdd(&hist[2047], zn);  // suppressed -0.0
    }
    __syncthreads();
    // suffix scan over 4096 bins, 16 bins/thread
    uint32_t loc[16], own = 0;
#pragma unroll
    for (int i = 0; i < 16; ++i) { loc[i] = hist[t * 16 + i]; own += loc[i]; }
    scnB[t] = own;
    __syncthreads();
    if (t == 0) {
      uint32_t acc = 0;
      for (int j = 255; j >= 0; --j) { uint32_t v = scnB[j]; scnB[j] = acc; acc += v; }
    }
    __syncthreads();
    uint32_t above = scnB[t];
    if (above < MAXDET && above + own >= MAXDET) {
      uint32_t cum = above;
      for (int i = 15; i >= 0; --i) {
        cum += loc[i];
        if (cum >= MAXDET) { sthr_s = (uint32_t)(t * 16 + i); break; }
      }
    }
    __syncthreads();
    uint32_t uthr = sthr_s << 20;
    for (int e = t; e < NPB; e += 256) {
      float v = hmb[e];
      bool kept = (v == nms_nbmax(hmb, e, v));
      float nv = kept ? v : 0.0f * v;
      uint32_t u = fsort(nv);
      if (u >= uthr) {
        uint32_t pos = atomicAdd(&lcnt, 1u);
        if (pos < SKCAP) sk[pos] = make_key(u, e);
      }
    }
    __syncthreads();
    n = lcnt; if (n > SKCAP) n = SKCAP;
  }
  __syncthreads();

  uint32_t m = 128; while (m < n) m <<= 1;
  for (uint32_t i = t; i < m; i += 256) if (i >= n) sk[i] = 0ull;
  __syncthreads();

  // bitonic sort descending by (value, ~fi): value desc, index asc on ties
  for (uint32_t k = 2; k <= m; k <<= 1) {
    for (uint32_t j = k >> 1; j > 0; j >>= 1) {
      for (uint32_t i = t; i < m; i += 256) {
        uint32_t ixj = i ^ j;
        if (ixj > i && ixj < m) {
          uint64_t a = sk[i], c = sk[ixj];
          bool desc = (i & k) == 0;
          if (desc ? (a < c) : (a > c)) { sk[i] = c; sk[ixj] = a; }
        }
      }
      __syncthreads();
    }
  }

  if (t < MAXDET) {
    uint64_t key = sk[t];
    uint32_t u = (uint32_t)(key >> 32);
    uint32_t fi = ~((uint32_t)key);
    float score = funsort(u);
    uint32_t c = fi % NCLS;
    uint32_t sp = (fi / NCLS) & (HWD - 1);
    float xs = (float)(sp & (WD - 1));
    float ys = (float)(sp >> 7);
    const float* gp = in + ((size_t)b * NCH + NCLS) * HWD + sp;
    float g0 = gp[0], g1 = gp[HWD], g2 = gp[2 * HWD], g3 = gp[3 * HWD];
    float* o = out + ((size_t)b * MAXDET + t) * 8;
    o[0] = (float)(c + 1);
    o[1] = score;
    o[2] = (4.0f * xs - g0) * (1.0f / 512.0f);
    o[3] = (4.0f * ys - g1) * (1.0f / 512.0f);
    o[4] = (4.0f * xs + g2) * (1.0f / 512.0f);
    o[5] = (4.0f * ys + g3) * (1.0f / 512.0f);
    o[6] = ys;
    o[7] = xs;
  }
}

extern "C" void kernel_launch(void* const* d_in, const int* in_sizes, int n_in,
                              void* d_out, int out_size, void* d_ws, size_t ws_size,
                              hipStream_t stream) {
  (void)in_sizes; (void)n_in; (void)out_size; (void)ws_size;
  const float* in = (const float*)d_in[0];
  float* out = (float*)d_out;
  uint8_t* ws = (uint8_t*)d_ws;

  uint32_t* cnt  = (uint32_t*)(ws + CNT_OFF);
  uint64_t* cand = (uint64_t*)(ws + CAND_OFF);

  k_pass1<<<dim3(NBLK, NBATCH), 256, 0, stream>>>(in, cand, cnt);
  k_finalize<<<NBATCH, 256, 0, stream>>>(in, cand, cnt, out);
}